// Round 1
// baseline (137.876 us; speedup 1.0000x reference)
//
#include <hip/hip_runtime.h>
#include <stdint.h>

#define IN_F 2048
#define OUT_F 2048
#define BM 128
#define BN 128
#define BK 128   // int8 elements per K-step == 128 bytes per LDS row

typedef int v4i __attribute__((ext_vector_type(4)));

__device__ __forceinline__ void gload_lds16(const void* g, void* l) {
    __builtin_amdgcn_global_load_lds(
        (const __attribute__((address_space(1))) void*)g,
        (__attribute__((address_space(3))) void*)l, 16, 0, 0);
}

// ---------------- Kernel 1: smooth-scale + per-token int8 quant ----------------
// One wave per token. Each lane handles 8 float4s (32 elems). Wave shfl max-reduce.
__global__ __launch_bounds__(256) void quant_kernel(
    const float* __restrict__ x, const float* __restrict__ ss,
    int8_t* __restrict__ xq, float* __restrict__ xscale, int T)
{
    const int wave = threadIdx.x >> 6;
    const int lane = threadIdx.x & 63;
    const int t = blockIdx.x * 4 + wave;
    if (t >= T) return;

    const float4* xrow = (const float4*)(x + (size_t)t * IN_F);
    const float4* ssv  = (const float4*)ss;

    float4 vals[8];
    float amax = 0.f;
#pragma unroll
    for (int it = 0; it < 8; ++it) {
        int idx = it * 64 + lane;          // 512 float4 per row = 8 * 64
        float4 v = xrow[idx];
        float4 s = ssv[idx];
        v.x *= s.x; v.y *= s.y; v.z *= s.z; v.w *= s.w;
        vals[it] = v;
        amax = fmaxf(amax, fmaxf(fmaxf(fabsf(v.x), fabsf(v.y)),
                                 fmaxf(fabsf(v.z), fabsf(v.w))));
    }
#pragma unroll
    for (int o = 32; o; o >>= 1) amax = fmaxf(amax, __shfl_xor(amax, o, 64));

    float scale = fmaxf(amax * (1.0f / 127.0f), 1e-8f);
    float inv = 1.0f / scale;              // precise division
    if (lane == 0) xscale[t] = scale;

    int* out = (int*)(xq + (size_t)t * IN_F);
#pragma unroll
    for (int it = 0; it < 8; ++it) {
        float4 v = vals[it];
        int q0 = (int)fminf(fmaxf(rintf(v.x * inv), -128.f), 127.f);
        int q1 = (int)fminf(fmaxf(rintf(v.y * inv), -128.f), 127.f);
        int q2 = (int)fminf(fmaxf(rintf(v.z * inv), -128.f), 127.f);
        int q3 = (int)fminf(fmaxf(rintf(v.w * inv), -128.f), 127.f);
        out[it * 64 + lane] = (q0 & 255) | ((q1 & 255) << 8) |
                              ((q2 & 255) << 16) | ((q3 & 255) << 24);
    }
}

// ---------------- Kernel 2: pack int32 weights -> int8 ----------------
__global__ __launch_bounds__(256) void pack_w_kernel(
    const int* __restrict__ w, int8_t* __restrict__ w8, int n4)
{
    int i = blockIdx.x * blockDim.x + threadIdx.x;   // packed-dword index
    if (i < n4) {
        int4 v = ((const int4*)w)[i];
        ((int*)w8)[i] = (v.x & 255) | ((v.y & 255) << 8) |
                        ((v.z & 255) << 16) | ((v.w & 255) << 24);
    }
}

// ---------------- Kernel 3: int8 MFMA GEMM + dequant epilogue ----------------
// C[t,o] = (sum_k xq[t,k]*w8[o,k]) * xscale[t] * wscale[o] + bias[o]
// 128x128 tile, K-step 128 bytes, 4 waves (2x2), 16x16x64 i8 MFMA, 4x4 frags/wave.
// LDS rows are 128B -> XOR-swizzle (row&7)<<4 applied on the *global source*
// (global_load_lds writes linearly) and on the ds_read address.
__global__ __launch_bounds__(256) void gemm_kernel(
    const int8_t* __restrict__ A,     // [M, IN_F] quantized activations
    const int8_t* __restrict__ B,     // [OUT_F, IN_F] int8 weights
    const float* __restrict__ xscale, // [M]
    const float* __restrict__ wscale, // [OUT_F]
    const float* __restrict__ bias,   // [OUT_F]
    float* __restrict__ C, int M)
{
    __shared__ __align__(16) int8_t sA[BM * BK];
    __shared__ __align__(16) int8_t sB[BN * BK];

    const int tid  = threadIdx.x;
    const int lane = tid & 63;
    const int wave = tid >> 6;
    const int wr = wave >> 1, wc = wave & 1;
    const int bm = blockIdx.y, bn = blockIdx.x;
    const size_t arow0 = (size_t)bm * BM;
    const size_t brow0 = (size_t)bn * BN;

    v4i acc[4][4] = {};

    // staging geometry: instr i, thread tid -> LDS linear off = i*4096 + tid*16
    const int off0 = tid * 16;
    const int r0 = off0 >> 7;        // 0..31
    const int ks = off0 & 127;       // 16B-granule column (swizzled slot)

    for (int kt = 0; kt < IN_F / BK; ++kt) {
        const int k0 = kt * BK;
#pragma unroll
        for (int i = 0; i < 4; ++i) {
            int row = r0 + i * 32;
            int kcol = ks ^ ((row & 7) << 4);   // inverse-swizzled global column
            gload_lds16(A + (arow0 + row) * (size_t)IN_F + k0 + kcol,
                        sA + i * 4096 + off0);
        }
#pragma unroll
        for (int i = 0; i < 4; ++i) {
            int row = r0 + i * 32;
            int kcol = ks ^ ((row & 7) << 4);
            gload_lds16(B + (brow0 + row) * (size_t)IN_F + k0 + kcol,
                        sB + i * 4096 + off0);
        }
        __syncthreads();

        const int hi = lane >> 4;
#pragma unroll
        for (int kk = 0; kk < 2; ++kk) {
            const int kloc = kk * 64 + hi * 16;
            v4i af[4], bf[4];
#pragma unroll
            for (int m = 0; m < 4; ++m) {
                int row = wr * 64 + m * 16 + (lane & 15);
                int addr = row * BK + (kloc ^ ((row & 7) << 4));
                af[m] = *(const v4i*)(sA + addr);
            }
#pragma unroll
            for (int n = 0; n < 4; ++n) {
                int col = wc * 64 + n * 16 + (lane & 15);
                int addr = col * BK + (kloc ^ ((col & 7) << 4));
                bf[n] = *(const v4i*)(sB + addr);
            }
#pragma unroll
            for (int m = 0; m < 4; ++m)
#pragma unroll
                for (int n = 0; n < 4; ++n)
                    acc[m][n] = __builtin_amdgcn_mfma_i32_16x16x64_i8(
                        af[m], bf[n], acc[m][n], 0, 0, 0);
        }
        __syncthreads();
    }

    // epilogue: C/D layout col = lane&15, row = (lane>>4)*4 + reg
    float wsc[4], bs[4];
    int cols[4];
#pragma unroll
    for (int n = 0; n < 4; ++n) {
        cols[n] = bn * BN + wc * 64 + n * 16 + (lane & 15);
        wsc[n] = wscale[cols[n]];
        bs[n]  = bias[cols[n]];
    }
#pragma unroll
    for (int m = 0; m < 4; ++m) {
        const int rbase = wr * 64 + m * 16 + ((lane >> 4) << 2);
#pragma unroll
        for (int r = 0; r < 4; ++r) {
            const size_t grow = arow0 + rbase + r;
            const float xs = xscale[grow];
            float* crow = C + grow * OUT_F;
#pragma unroll
            for (int n = 0; n < 4; ++n)
                crow[cols[n]] = (float)acc[m][n][r] * xs * wsc[n] + bs[n];
        }
    }
}

extern "C" void kernel_launch(void* const* d_in, const int* in_sizes, int n_in,
                              void* d_out, int out_size, void* d_ws, size_t ws_size,
                              hipStream_t stream)
{
    const float* x      = (const float*)d_in[0];
    const float* ss     = (const float*)d_in[1];
    const float* wscale = (const float*)d_in[2];
    const float* bias   = (const float*)d_in[3];
    const int*   w32    = (const int*)d_in[4];   // integer inputs arrive as int32
    float* out = (float*)d_out;

    const int T = in_sizes[0] / IN_F;            // 16384 tokens

    // workspace layout: xq [T*IN_F i8] | xscale [T f32] | w8 [OUT_F*IN_F i8]
    int8_t* xq     = (int8_t*)d_ws;
    float*  xscale = (float*)((char*)d_ws + (size_t)T * IN_F);
    int8_t* w8     = (int8_t*)((char*)d_ws + (size_t)T * IN_F + (size_t)T * 4);

    quant_kernel<<<dim3((T + 3) / 4), dim3(256), 0, stream>>>(x, ss, xq, xscale, T);
    pack_w_kernel<<<dim3((OUT_F * IN_F / 4 + 255) / 256), dim3(256), 0, stream>>>(
        w32, w8, OUT_F * IN_F / 4);
    gemm_kernel<<<dim3(OUT_F / BN, T / BM), dim3(256), 0, stream>>>(
        xq, w8, xscale, wscale, bias, out, T);
}

// Round 2
// 124.645 us; speedup vs baseline: 1.1061x; 1.1061x over previous
//
#include <hip/hip_runtime.h>
#include <stdint.h>

#define IN_F 2048
#define OUT_F 2048
#define BM 256
#define BN 256
#define BKB 64              // K bytes (= int8 elems) per K-tile
#define NT (IN_F / BKB)     // 32 K-tiles

typedef int v4i __attribute__((ext_vector_type(4)));

__device__ __forceinline__ void gload_lds16(const void* g, void* l) {
    __builtin_amdgcn_global_load_lds(
        (const __attribute__((address_space(1))) void*)g,
        (__attribute__((address_space(3))) void*)l, 16, 0, 0);
}

// ---------------- Kernel 1: smooth-scale + per-token int8 quant ----------------
__global__ __launch_bounds__(256) void quant_kernel(
    const float* __restrict__ x, const float* __restrict__ ss,
    int8_t* __restrict__ xq, float* __restrict__ xscale, int T)
{
    const int wave = threadIdx.x >> 6;
    const int lane = threadIdx.x & 63;
    const int t = blockIdx.x * 4 + wave;
    if (t >= T) return;

    const float4* xrow = (const float4*)(x + (size_t)t * IN_F);
    const float4* ssv  = (const float4*)ss;

    float4 vals[8];
    float amax = 0.f;
#pragma unroll
    for (int it = 0; it < 8; ++it) {
        int idx = it * 64 + lane;
        float4 v = xrow[idx];
        float4 s = ssv[idx];
        v.x *= s.x; v.y *= s.y; v.z *= s.z; v.w *= s.w;
        vals[it] = v;
        amax = fmaxf(amax, fmaxf(fmaxf(fabsf(v.x), fabsf(v.y)),
                                 fmaxf(fabsf(v.z), fabsf(v.w))));
    }
#pragma unroll
    for (int o = 32; o; o >>= 1) amax = fmaxf(amax, __shfl_xor(amax, o, 64));

    float scale = fmaxf(amax * (1.0f / 127.0f), 1e-8f);
    float inv = 1.0f / scale;
    if (lane == 0) xscale[t] = scale;

    int* out = (int*)(xq + (size_t)t * IN_F);
#pragma unroll
    for (int it = 0; it < 8; ++it) {
        float4 v = vals[it];
        int q0 = (int)fminf(fmaxf(rintf(v.x * inv), -128.f), 127.f);
        int q1 = (int)fminf(fmaxf(rintf(v.y * inv), -128.f), 127.f);
        int q2 = (int)fminf(fmaxf(rintf(v.z * inv), -128.f), 127.f);
        int q3 = (int)fminf(fmaxf(rintf(v.w * inv), -128.f), 127.f);
        out[it * 64 + lane] = (q0 & 255) | ((q1 & 255) << 8) |
                              ((q2 & 255) << 16) | ((q3 & 255) << 24);
    }
}

// ---------------- Kernel 2: pack int32 weights -> int8 ----------------
__global__ __launch_bounds__(256) void pack_w_kernel(
    const int* __restrict__ w, int8_t* __restrict__ w8, int n4)
{
    int i = blockIdx.x * blockDim.x + threadIdx.x;
    if (i < n4) {
        int4 v = ((const int4*)w)[i];
        ((int*)w8)[i] = (v.x & 255) | ((v.y & 255) << 8) |
                        ((v.z & 255) << 16) | ((v.w & 255) << 24);
    }
}

// ---------------- Kernel 3: 256x256 2-phase/K-tile pipelined i8 GEMM ----------------
// Schedule (per steady K-tile t, sets double-buffered, issue order Ah0,Bh0,Bh1,Ah1):
//  p1: ds_read B(all)+A(h0) | stage Ah0,Bh0(t+1) | bar | 16 MFMA | vmcnt(2) | bar
//  p2: ds_read A(h1)        | stage Bh1,Ah1(t+1) | bar | 16 MFMA | vmcnt(1) | bar
// Ledger: end-p2(t-1) vmcnt(1) guarantees {Ah0,Bh0,Bh1}(t) for p1; end-p1(t)
// vmcnt(2) guarantees Ah1(t) for p2. Loads never drain to 0 in steady state.
__global__ __launch_bounds__(512, 2) void gemm_kernel(
    const int8_t* __restrict__ Ag,    // [M, IN_F]
    const int8_t* __restrict__ Bg,    // [OUT_F, IN_F]
    const float* __restrict__ xscale,
    const float* __restrict__ wscale,
    const float* __restrict__ bias,
    float* __restrict__ C, int M)
{
    __shared__ __align__(16) int8_t smem[2 * 2 * BM * BKB];   // [set][op][256*64] = 64 KB

    const int tid  = threadIdx.x;
    const int lane = tid & 63;
    const int wave = tid >> 6;
    const int wr = wave >> 2;         // 0..1 (M)
    const int wc = wave & 3;          // 0..3 (N)
    const int l15 = lane & 15, hi = lane >> 4;

    // XCD-bijective swizzle: 512 blocks, 8 XCDs, 64 per chunk
    const int lb  = blockIdx.x;
    const int swb = (lb & 7) * 64 + (lb >> 3);
    const int bm = swb >> 3;          // 0..63
    const int bn = swb & 7;           // 0..7
    const size_t arow0 = (size_t)bm * BM;
    const size_t brow0 = (size_t)bn * BN;

    // LDS bank swizzle for 64B rows: byte col ^= ((row&3)^((row>>2)&3))<<4
    const int sw    = (((lane & 3) ^ ((lane >> 2) & 3)) << 4);
    const int rdcol = (hi << 4) ^ sw;

    // staging geometry: thread -> row (tid>>2) of half, col (tid&3)*16
    const int st_lrow = tid >> 2;
    const int st_gcol = ((tid & 3) << 4) ^ ((((tid >> 2) & 3) ^ ((tid >> 4) & 3)) << 4);

#define STAGE(SET, OP, GPTR, ROW0, H, KOFF)                                          \
    gload_lds16((GPTR) + ((ROW0) + (H) * 128 + st_lrow) * (size_t)IN_F + (KOFF) + st_gcol, \
                smem + (SET) * 32768 + (OP) * 16384 + (H) * 8192 + tid * 16)

#define LOAD_A(SBASE, ASEL, AF)                                      \
    do { _Pragma("unroll") for (int m_ = 0; m_ < 4; ++m_) {          \
        int row_ = (ASEL) * 128 + wr * 64 + m_ * 16 + l15;           \
        AF[m_] = *(const v4i*)((SBASE) + row_ * 64 + rdcol);         \
    } } while (0)

#define LOAD_B_ALL(SBASE, BF)                                        \
    do { _Pragma("unroll") for (int n_ = 0; n_ < 4; ++n_) {          \
        int row_ = (n_ >> 1) * 128 + wc * 32 + (n_ & 1) * 16 + l15;  \
        BF[n_] = *(const v4i*)((SBASE) + row_ * 64 + rdcol);         \
    } } while (0)

#define MFMA_PHASE(ASEL, AF, BF)                                                  \
    do { _Pragma("unroll") for (int m_ = 0; m_ < 4; ++m_)                         \
         _Pragma("unroll") for (int n_ = 0; n_ < 4; ++n_)                         \
        acc[(ASEL) * 4 + m_][n_] = __builtin_amdgcn_mfma_i32_16x16x64_i8(         \
            AF[m_], BF[n_], acc[(ASEL) * 4 + m_][n_], 0, 0, 0); } while (0)

    v4i acc[8][4] = {};

    // prologue: stage tile 0 into set 0 (order Ah0,Bh0,Bh1,Ah1)
    STAGE(0, 0, Ag, arow0, 0, 0);
    STAGE(0, 1, Bg, brow0, 0, 0);
    STAGE(0, 1, Bg, brow0, 1, 0);
    STAGE(0, 0, Ag, arow0, 1, 0);
    asm volatile("s_waitcnt vmcnt(1)" ::: "memory");
    __builtin_amdgcn_s_barrier();

    for (int kt = 0; kt < NT - 1; ++kt) {
        const int cur = kt & 1, nxt = cur ^ 1;
        const int8_t* sA = smem + cur * 32768;
        const int8_t* sB = sA + 16384;
        const int kn = (kt + 1) * BKB;
        v4i bf[4], af[4];

        // phase 1
        LOAD_B_ALL(sB, bf);
        LOAD_A(sA, 0, af);
        STAGE(nxt, 0, Ag, arow0, 0, kn);
        STAGE(nxt, 1, Bg, brow0, 0, kn);
        __builtin_amdgcn_s_barrier();
        __builtin_amdgcn_s_setprio(1);
        MFMA_PHASE(0, af, bf);
        __builtin_amdgcn_s_setprio(0);
        asm volatile("s_waitcnt vmcnt(2)" ::: "memory");
        __builtin_amdgcn_s_barrier();

        // phase 2
        LOAD_A(sA, 1, af);
        STAGE(nxt, 1, Bg, brow0, 1, kn);
        STAGE(nxt, 0, Ag, arow0, 1, kn);
        __builtin_amdgcn_s_barrier();
        __builtin_amdgcn_s_setprio(1);
        MFMA_PHASE(1, af, bf);
        __builtin_amdgcn_s_setprio(0);
        asm volatile("s_waitcnt vmcnt(1)" ::: "memory");
        __builtin_amdgcn_s_barrier();
    }
    {   // tail K-tile (NT-1, set 1)
        const int8_t* sA = smem + 32768;
        const int8_t* sB = sA + 16384;
        v4i bf[4], af[4];
        LOAD_B_ALL(sB, bf);
        LOAD_A(sA, 0, af);
        __builtin_amdgcn_s_barrier();
        __builtin_amdgcn_s_setprio(1);
        MFMA_PHASE(0, af, bf);
        __builtin_amdgcn_s_setprio(0);
        asm volatile("s_waitcnt vmcnt(0)" ::: "memory");
        __builtin_amdgcn_s_barrier();
        LOAD_A(sA, 1, af);
        __builtin_amdgcn_s_setprio(1);
        MFMA_PHASE(1, af, bf);
        __builtin_amdgcn_s_setprio(0);
    }

    // epilogue: C/D layout col = lane&15, row = (lane>>4)*4 + reg
    float wsc[4], bs[4];
    int gcol[4];
#pragma unroll
    for (int n = 0; n < 4; ++n) {
        gcol[n] = bn * BN + (n >> 1) * 128 + wc * 32 + (n & 1) * 16 + l15;
        wsc[n] = wscale[gcol[n]];
        bs[n]  = bias[gcol[n]];
    }
#pragma unroll
    for (int m = 0; m < 8; ++m) {
        const int rbase = (m >> 2) * 128 + wr * 64 + (m & 3) * 16 + hi * 4;
#pragma unroll
        for (int r = 0; r < 4; ++r) {
            const size_t grow = arow0 + rbase + r;
            const float xs = xscale[grow];
            float* crow = C + grow * OUT_F;
#pragma unroll
            for (int n = 0; n < 4; ++n)
                crow[gcol[n]] = (float)acc[m][n][r] * xs * wsc[n] + bs[n];
        }
    }
#undef STAGE
#undef LOAD_A
#undef LOAD_B_ALL
#undef MFMA_PHASE
}

extern "C" void kernel_launch(void* const* d_in, const int* in_sizes, int n_in,
                              void* d_out, int out_size, void* d_ws, size_t ws_size,
                              hipStream_t stream)
{
    const float* x      = (const float*)d_in[0];
    const float* ss     = (const float*)d_in[1];
    const float* wscale = (const float*)d_in[2];
    const float* bias   = (const float*)d_in[3];
    const int*   w32    = (const int*)d_in[4];
    float* out = (float*)d_out;

    const int T = in_sizes[0] / IN_F;   // 16384

    int8_t* xq     = (int8_t*)d_ws;
    float*  xscale = (float*)((char*)d_ws + (size_t)T * IN_F);
    int8_t* w8     = (int8_t*)((char*)d_ws + (size_t)T * IN_F + (size_t)T * 4);

    quant_kernel<<<dim3((T + 3) / 4), dim3(256), 0, stream>>>(x, ss, xq, xscale, T);
    pack_w_kernel<<<dim3((OUT_F * IN_F / 4 + 255) / 256), dim3(256), 0, stream>>>(
        w32, w8, OUT_F * IN_F / 4);
    gemm_kernel<<<dim3((T / BM) * (OUT_F / BN)), dim3(512), 0, stream>>>(
        xq, w8, xscale, wscale, bias, out, T);
}

// Round 3
// 115.649 us; speedup vs baseline: 1.1922x; 1.0778x over previous
//
#include <hip/hip_runtime.h>
#include <stdint.h>

#define IN_F 2048
#define OUT_F 2048
#define BM 256
#define BN 256
#define BKB 128             // K bytes per K-tile (128B LDS rows)
#define NT (IN_F / BKB)     // 16 K-tiles

typedef int v4i __attribute__((ext_vector_type(4)));

__device__ __forceinline__ void gload_lds16(const void* g, void* l) {
    __builtin_amdgcn_global_load_lds(
        (const __attribute__((address_space(1))) void*)g,
        (__attribute__((address_space(3))) void*)l, 16, 0, 0);
}

// ---------------- Kernel 1: smooth-scale + per-token int8 quant ----------------
__global__ __launch_bounds__(256) void quant_kernel(
    const float* __restrict__ x, const float* __restrict__ ss,
    int8_t* __restrict__ xq, float* __restrict__ xscale, int T)
{
    const int wave = threadIdx.x >> 6;
    const int lane = threadIdx.x & 63;
    const int t = blockIdx.x * 4 + wave;
    if (t >= T) return;

    const float4* xrow = (const float4*)(x + (size_t)t * IN_F);
    const float4* ssv  = (const float4*)ss;

    float4 vals[8];
    float amax = 0.f;
#pragma unroll
    for (int it = 0; it < 8; ++it) {
        int idx = it * 64 + lane;
        float4 v = xrow[idx];
        float4 s = ssv[idx];
        v.x *= s.x; v.y *= s.y; v.z *= s.z; v.w *= s.w;
        vals[it] = v;
        amax = fmaxf(amax, fmaxf(fmaxf(fabsf(v.x), fabsf(v.y)),
                                 fmaxf(fabsf(v.z), fabsf(v.w))));
    }
#pragma unroll
    for (int o = 32; o; o >>= 1) amax = fmaxf(amax, __shfl_xor(amax, o, 64));

    float scale = fmaxf(amax * (1.0f / 127.0f), 1e-8f);
    float inv = 1.0f / scale;
    if (lane == 0) xscale[t] = scale;

    int* out = (int*)(xq + (size_t)t * IN_F);
#pragma unroll
    for (int it = 0; it < 8; ++it) {
        float4 v = vals[it];
        int q0 = (int)fminf(fmaxf(rintf(v.x * inv), -128.f), 127.f);
        int q1 = (int)fminf(fmaxf(rintf(v.y * inv), -128.f), 127.f);
        int q2 = (int)fminf(fmaxf(rintf(v.z * inv), -128.f), 127.f);
        int q3 = (int)fminf(fmaxf(rintf(v.w * inv), -128.f), 127.f);
        out[it * 64 + lane] = (q0 & 255) | ((q1 & 255) << 8) |
                              ((q2 & 255) << 16) | ((q3 & 255) << 24);
    }
}

// ---------------- Kernel 2: pack int32 weights -> int8 ----------------
__global__ __launch_bounds__(256) void pack_w_kernel(
    const int* __restrict__ w, int8_t* __restrict__ w8, int n4)
{
    int i = blockIdx.x * blockDim.x + threadIdx.x;
    if (i < n4) {
        int4 v = ((const int4*)w)[i];
        ((int*)w8)[i] = (v.x & 255) | ((v.y & 255) << 8) |
                        ((v.z & 255) << 16) | ((v.w & 255) << 24);
    }
}

// ---------------- Kernel 3: 256x256 4-phase/K-tile (m201-style) i8 GEMM ----------------
// LDS: set(64KB) = A[256][128] (32KB) | B[256][128] (32KB); 2 sets = 128KB.
// Granule swizzle: 16B-slot s of row r holds granule s^(r&7) (write via pre-swizzled
// global source col; read via slot = g^(r&7)).
// Per K-tile t (4 phases): p0{rdA0-3,rdBlo | stage A(t+1).h0} p1{rdBhi | stage A(t+1).h1}
// p2{rdA4-7 | stage B(t+2).h0} p3{stage B(t+2).h1 | vmcnt(4)}. Each phase:
// reads/stage, bar, setprio1, 16 MFMA, setprio0, bar. B(t) reads done by p1-bar2,
// A(t) by p2-bar2 -> the into-current-set B stages at p2/p3 are race-free.
__global__ __launch_bounds__(512, 2) void gemm_kernel(
    const int8_t* __restrict__ Ag,    // [M, IN_F]
    const int8_t* __restrict__ Bg,    // [OUT_F, IN_F]
    const float* __restrict__ xscale,
    const float* __restrict__ wscale,
    const float* __restrict__ bias,
    float* __restrict__ C, int M)
{
    __shared__ __align__(16) int8_t smem[2 * 65536];   // 128 KB

    const int tid  = threadIdx.x;
    const int lane = tid & 63;
    const int wave = tid >> 6;
    const int wr = wave >> 2;         // 0..1 (M half)
    const int wc = wave & 3;          // 0..3 (N quarter)
    const int l15 = lane & 15, hi = lane >> 4;
    const int sl = l15 & 7;           // read-swizzle row bits

    // XCD-bijective swizzle: 512 blocks, 8 XCDs, 64 per chunk
    const int lb  = blockIdx.x;
    const int swb = (lb & 7) * 64 + (lb >> 3);
    const int bm = swb >> 3;          // 0..63
    const int bn = swb & 7;           // 0..7
    const size_t arow0 = (size_t)bm * BM;
    const size_t brow0 = (size_t)bn * BN;

    // staging: thread tid covers row (tid>>3), writes LDS slot (tid&7) of that row;
    // global source granule = (tid&7) ^ (row&7)
    const int st_r = tid >> 3;
    const int st_c = ((tid & 7) ^ ((tid >> 3) & 7)) << 4;

#define STAGE(DSTBASE, GPTR, GROW0, H, TILE)                                       \
    do { _Pragma("unroll") for (int i_ = 0; i_ < 2; ++i_)                          \
        gload_lds16((GPTR) + ((GROW0) + (H) * 128 + i_ * 64 + st_r) * (size_t)IN_F \
                        + (size_t)((TILE) * 128 + st_c),                           \
                    (DSTBASE) + (H) * 16384 + i_ * 8192 + tid * 16);               \
    } while (0)

#define RD_A(M0)                                                                   \
    do { _Pragma("unroll") for (int m_ = 0; m_ < 4; ++m_)                          \
         _Pragma("unroll") for (int ks_ = 0; ks_ < 2; ++ks_)                       \
        a[m_][ks_] = *(const v4i*)(pA + ((M0) + m_) * 2048 +                       \
                                   (((ks_ * 4 + hi) ^ sl) << 4));                  \
    } while (0)

#define RD_B(BF, N0)                                                               \
    do { _Pragma("unroll") for (int n_ = 0; n_ < 2; ++n_)                          \
         _Pragma("unroll") for (int ks_ = 0; ks_ < 2; ++ks_)                       \
        BF[n_][ks_] = *(const v4i*)(pB + ((N0) + n_) * 2048 +                      \
                                    (((ks_ * 4 + hi) ^ sl) << 4));                 \
    } while (0)

#define MF(M0, N0, BF)                                                             \
    do { _Pragma("unroll") for (int m_ = 0; m_ < 4; ++m_)                          \
         _Pragma("unroll") for (int n_ = 0; n_ < 2; ++n_)                          \
         _Pragma("unroll") for (int ks_ = 0; ks_ < 2; ++ks_)                       \
        acc[(M0) + m_][(N0) + n_] = __builtin_amdgcn_mfma_i32_16x16x64_i8(         \
            a[m_][ks_], BF[n_][ks_], acc[(M0) + m_][(N0) + n_], 0, 0, 0);          \
    } while (0)

#define PH_BAR __builtin_amdgcn_s_barrier()
#define PRIO1 __builtin_amdgcn_s_setprio(1)
#define PRIO0 __builtin_amdgcn_s_setprio(0)
#define VMW4 asm volatile("s_waitcnt vmcnt(4)" ::: "memory")
#define VMW0 asm volatile("s_waitcnt vmcnt(0)" ::: "memory")
#define VNOP ((void)0)

#define KTILE(CS, NS, TA, TB, DO_SA, DO_SB, VMASM)                                 \
    do {                                                                           \
        const char* pA = (const char*)(CS) + (wr * 128 + l15) * 128;               \
        const char* pB = (const char*)(CS) + 32768 + (wc * 64 + l15) * 128;        \
        RD_A(0); RD_B(blo, 0);                                                     \
        if (DO_SA) STAGE((NS), Ag, arow0, 0, TA);                                  \
        PH_BAR; PRIO1; MF(0, 0, blo); PRIO0; PH_BAR;                               \
        RD_B(bhi, 2);                                                              \
        if (DO_SA) STAGE((NS), Ag, arow0, 1, TA);                                  \
        PH_BAR; PRIO1; MF(0, 2, bhi); PRIO0; PH_BAR;                               \
        RD_A(4);                                                                   \
        if (DO_SB) STAGE((CS) + 32768, Bg, brow0, 0, TB);                          \
        PH_BAR; PRIO1; MF(4, 0, blo); PRIO0; PH_BAR;                               \
        if (DO_SB) STAGE((CS) + 32768, Bg, brow0, 1, TB);                          \
        PH_BAR; PRIO1; MF(4, 2, bhi); PRIO0;                                       \
        VMASM;                                                                     \
        PH_BAR;                                                                    \
    } while (0)

    v4i acc[8][4] = {};
    v4i a[4][2], blo[2][2], bhi[2][2];

    char* s0 = (char*)smem;
    char* s1 = s0 + 65536;

    // prologue: A(0), B(0) -> set0; B(1) -> set1. vmcnt(4) lets B(1) fly.
    STAGE(s0, Ag, arow0, 0, 0);
    STAGE(s0, Ag, arow0, 1, 0);
    STAGE(s0 + 32768, Bg, brow0, 0, 0);
    STAGE(s0 + 32768, Bg, brow0, 1, 0);
    STAGE(s1 + 32768, Bg, brow0, 0, 1);
    STAGE(s1 + 32768, Bg, brow0, 1, 1);
    VMW4;
    PH_BAR;

#pragma unroll 1
    for (int t = 0; t < 14; t += 2) {
        KTILE(s0, s1, t + 1, t + 2, true, true, VMW4);
        KTILE(s1, s0, t + 2, t + 3, true, true, VMW4);
    }
    KTILE(s0, s1, 15, 0, true, false, VMW0);   // tile 14
    KTILE(s1, s0, 0, 0, false, false, VNOP);   // tile 15

    // epilogue: C/D layout col = lane&15, row = hi*4 + reg
    float wsc[4], bs[4];
    int gcol[4];
#pragma unroll
    for (int n = 0; n < 4; ++n) {
        gcol[n] = bn * BN + wc * 64 + n * 16 + l15;
        wsc[n] = wscale[gcol[n]];
        bs[n]  = bias[gcol[n]];
    }
#pragma unroll
    for (int m = 0; m < 8; ++m) {
        const int rbase = wr * 128 + m * 16 + hi * 4;
#pragma unroll
        for (int r = 0; r < 4; ++r) {
            const size_t grow = arow0 + rbase + r;
            const float xs = xscale[grow];
            float* crow = C + grow * OUT_F;
#pragma unroll
            for (int n = 0; n < 4; ++n)
                crow[gcol[n]] = (float)acc[m][n][r] * xs * wsc[n] + bs[n];
        }
    }
#undef STAGE
#undef RD_A
#undef RD_B
#undef MF
#undef KTILE
}

extern "C" void kernel_launch(void* const* d_in, const int* in_sizes, int n_in,
                              void* d_out, int out_size, void* d_ws, size_t ws_size,
                              hipStream_t stream)
{
    const float* x      = (const float*)d_in[0];
    const float* ss     = (const float*)d_in[1];
    const float* wscale = (const float*)d_in[2];
    const float* bias   = (const float*)d_in[3];
    const int*   w32    = (const int*)d_in[4];
    float* out = (float*)d_out;

    const int T = in_sizes[0] / IN_F;   // 16384

    int8_t* xq     = (int8_t*)d_ws;
    float*  xscale = (float*)((char*)d_ws + (size_t)T * IN_F);
    int8_t* w8     = (int8_t*)((char*)d_ws + (size_t)T * IN_F + (size_t)T * 4);

    quant_kernel<<<dim3((T + 3) / 4), dim3(256), 0, stream>>>(x, ss, xq, xscale, T);
    pack_w_kernel<<<dim3((OUT_F * IN_F / 4 + 255) / 256), dim3(256), 0, stream>>>(
        w32, w8, OUT_F * IN_F / 4);
    gemm_kernel<<<dim3((T / BM) * (OUT_F / BN)), dim3(512), 0, stream>>>(
        xq, w8, xscale, wscale, bias, out, T);
}

// Round 5
// 112.069 us; speedup vs baseline: 1.2303x; 1.0319x over previous
//
#include <hip/hip_runtime.h>
#include <stdint.h>

#define IN_F 2048
#define OUT_F 2048
#define BM 256
#define BN 256
#define NT 16               // K-tiles of 128 bytes

typedef int v4i  __attribute__((ext_vector_type(4)));
typedef int v16i __attribute__((ext_vector_type(16)));

__device__ __forceinline__ void gload_lds16(const void* g, void* l) {
    __builtin_amdgcn_global_load_lds(
        (const __attribute__((address_space(1))) void*)g,
        (__attribute__((address_space(3))) void*)l, 16, 0, 0);
}

// ---------------- Kernel 1: smooth-scale + per-token int8 quant ----------------
__global__ __launch_bounds__(256) void quant_kernel(
    const float* __restrict__ x, const float* __restrict__ ss,
    int8_t* __restrict__ xq, float* __restrict__ xscale, int T)
{
    const int wave = threadIdx.x >> 6;
    const int lane = threadIdx.x & 63;
    const int t = blockIdx.x * 4 + wave;
    if (t >= T) return;

    const float4* xrow = (const float4*)(x + (size_t)t * IN_F);
    const float4* ssv  = (const float4*)ss;

    float4 vals[8];
    float amax = 0.f;
#pragma unroll
    for (int it = 0; it < 8; ++it) {
        int idx = it * 64 + lane;
        float4 v = xrow[idx];
        float4 s = ssv[idx];
        v.x *= s.x; v.y *= s.y; v.z *= s.z; v.w *= s.w;
        vals[it] = v;
        amax = fmaxf(amax, fmaxf(fmaxf(fabsf(v.x), fabsf(v.y)),
                                 fmaxf(fabsf(v.z), fabsf(v.w))));
    }
#pragma unroll
    for (int o = 32; o; o >>= 1) amax = fmaxf(amax, __shfl_xor(amax, o, 64));

    float scale = fmaxf(amax * (1.0f / 127.0f), 1e-8f);
    float inv = 1.0f / scale;
    if (lane == 0) xscale[t] = scale;

    int* out = (int*)(xq + (size_t)t * IN_F);
#pragma unroll
    for (int it = 0; it < 8; ++it) {
        float4 v = vals[it];
        int q0 = (int)fminf(fmaxf(rintf(v.x * inv), -128.f), 127.f);
        int q1 = (int)fminf(fmaxf(rintf(v.y * inv), -128.f), 127.f);
        int q2 = (int)fminf(fmaxf(rintf(v.z * inv), -128.f), 127.f);
        int q3 = (int)fminf(fmaxf(rintf(v.w * inv), -128.f), 127.f);
        out[it * 64 + lane] = (q0 & 255) | ((q1 & 255) << 8) |
                              ((q2 & 255) << 16) | ((q3 & 255) << 24);
    }
}

// ---------------- Kernel 2: pack W into MFMA-fragment order ----------------
// Fragment (colblk, kt, ks), lane l holds 16B: col = colblk*32 + (l&31),
// k = kt*128 + ks*32 + (l>>5)*16 + 0..15.
// Byte addr = colblk*65536 + kt*4096 + ks*1024 + l*16.
__global__ __launch_bounds__(256) void pack_wfrag_kernel(
    const int* __restrict__ w, int8_t* __restrict__ w8f)
{
    const int tau = blockIdx.x * 256 + threadIdx.x;   // 0..262143
    const int lane = tau & 63;
    const int rest = tau >> 6;
    const int ks = rest & 3;
    const int kt = (rest >> 2) & 15;
    const int colblk = rest >> 6;
    const int col = colblk * 32 + (lane & 31);
    const int kbase = kt * 128 + ks * 32 + (lane >> 5) * 16;
    const int* src = w + (size_t)col * IN_F + kbase;
    int out[4];
#pragma unroll
    for (int d = 0; d < 4; ++d) {
        int4 v = *(const int4*)(src + d * 4);
        out[d] = (v.x & 255) | ((v.y & 255) << 8) |
                 ((v.z & 255) << 16) | ((v.w & 255) << 24);
    }
    *(int4*)(w8f + (size_t)tau * 16) = *(const int4*)out;
}

// ---------------- Kernel 3: 256x256 i8 GEMM, A-in-LDS (3-deep), B-direct ----------------
// 8 waves (2M x 4N), per-wave 128x64, mfma_i32_32x32x32_i8, acc 4x2 v16i.
// Per K-tile: [load B(t+1) regs x8, stage A(t+2) x4 gload_lds] -> 16 ds_read -> 32 MFMA
// -> vmcnt(4) -> barrier. One barrier per tile; loads never drain to 0 until tail.
__global__ __launch_bounds__(512, 2) void gemm_kernel(
    const int8_t* __restrict__ Ag,    // [M, IN_F] quantized activations
    const int8_t* __restrict__ Bf,    // fragment-ordered weights
    const float* __restrict__ xscale,
    const float* __restrict__ wscale,
    const float* __restrict__ bias,
    float* __restrict__ C, int M)
{
    __shared__ __align__(16) int8_t smem[3 * 32768];   // 96 KB: 3 A-slots

    const int tid  = threadIdx.x;
    const int lane = tid & 63;
    const int wave = tid >> 6;
    const int wr = wave >> 2;          // 0..1 (M half)
    const int wc = wave & 3;           // 0..3 (N quarter)
    const int l31 = lane & 31, hi2 = lane >> 5;
    const int asw = l31 & 7;

    // XCD-bijective swizzle: 512 blocks, 8 XCDs, 64 per chunk
    const int lb  = blockIdx.x;
    const int swb = (lb & 7) * 64 + (lb >> 3);
    const int bm = swb >> 3;           // 0..63
    const int bn = swb & 7;            // 0..7
    const size_t arow0 = (size_t)bm * BM;

    // A staging: thread covers row tid>>3, LDS slot (tid&7); global granule pre-swizzled
    const int st_r = tid >> 3;
    const int st_c = ((tid & 7) ^ ((tid >> 3) & 7)) << 4;

    // A ds_read base: row = wr*128 + m*32 + l31; granule g = ks*2+hi2, col = (g^asw)*16
    const int aoff = (wr * 128 + l31) * 128;

    // B fragment base for this wave (colblk stride = 65536 bytes)
    const int8_t* bbase = Bf + (size_t)(bn * 8 + wc * 2) * 65536 + lane * 16;

#define STAGE_A(SLOTI, T)                                                        \
    do { _Pragma("unroll") for (int h_ = 0; h_ < 2; ++h_)                        \
         _Pragma("unroll") for (int i_ = 0; i_ < 2; ++i_)                        \
        gload_lds16(Ag + (arow0 + h_ * 128 + i_ * 64 + st_r) * (size_t)IN_F     \
                        + (size_t)((T) * 128) + st_c,                            \
                    (int8_t*)smem + (SLOTI) * 32768 + h_ * 16384 + i_ * 8192     \
                        + tid * 16);                                             \
    } while (0)

#define LOADB(DST, T)                                                            \
    do { _Pragma("unroll") for (int n_ = 0; n_ < 2; ++n_)                        \
         _Pragma("unroll") for (int k_ = 0; k_ < 4; ++k_)                        \
        DST[n_ * 4 + k_] = *(const v4i*)(bbase + n_ * 65536 + (T) * 4096         \
                                         + k_ * 1024);                           \
    } while (0)

#define COMPUTE(SLOTI, B)                                                        \
    do { const int8_t* sp_ = (const int8_t*)smem + (SLOTI) * 32768 + aoff;       \
        _Pragma("unroll") for (int ks_ = 0; ks_ < 4; ++ks_) {                    \
            v4i af_[4];                                                          \
            _Pragma("unroll") for (int m_ = 0; m_ < 4; ++m_)                     \
                af_[m_] = *(const v4i*)(sp_ + m_ * 4096 +                        \
                                        (((ks_ * 2 + hi2) ^ asw) << 4));         \
            __builtin_amdgcn_s_setprio(1);                                       \
            _Pragma("unroll") for (int m_ = 0; m_ < 4; ++m_)                     \
            _Pragma("unroll") for (int n_ = 0; n_ < 2; ++n_)                     \
                acc[m_][n_] = __builtin_amdgcn_mfma_i32_32x32x32_i8(             \
                    af_[m_], B[n_ * 4 + ks_], acc[m_][n_], 0, 0, 0);             \
            __builtin_amdgcn_s_setprio(0);                                       \
        }                                                                        \
    } while (0)

#define TILE(BCUR, BNXT, T)                                                      \
    do {                                                                         \
        if ((T) < 15) LOADB(BNXT, (T) + 1);                                      \
        if ((T) < 14) STAGE_A(((T) + 2) % 3, (T) + 2);                           \
        COMPUTE((T) % 3, BCUR);                                                  \
        if ((T) < 14) {                                                          \
            asm volatile("s_waitcnt vmcnt(4)" ::: "memory");                     \
            __builtin_amdgcn_s_barrier();                                        \
        } else if ((T) == 14) {                                                  \
            asm volatile("s_waitcnt vmcnt(0)" ::: "memory");                     \
            __builtin_amdgcn_s_barrier();                                        \
        }                                                                        \
    } while (0)

    v16i acc[4][2] = {};
    v4i B0[8], B1[8];

    // prologue: A(0)->slot0, A(1)->slot1, B(0) regs
    STAGE_A(0, 0);
    STAGE_A(1, 1);
    LOADB(B0, 0);
    asm volatile("s_waitcnt vmcnt(0)" ::: "memory");
    __builtin_amdgcn_s_barrier();

#pragma unroll
    for (int t = 0; t < NT; t += 2) {
        TILE(B0, B1, t);
        TILE(B1, B0, t + 1);
    }

    // epilogue: 32x32 C/D layout col = lane&31, row = (reg&3) + 8*(reg>>2) + 4*hi2
    float wsc[2], bs[2];
    int gcol[2];
#pragma unroll
    for (int n = 0; n < 2; ++n) {
        gcol[n] = bn * BN + wc * 64 + n * 32 + l31;
        wsc[n] = wscale[gcol[n]];
        bs[n]  = bias[gcol[n]];
    }
#pragma unroll
    for (int m = 0; m < 4; ++m) {
#pragma unroll
        for (int reg = 0; reg < 16; ++reg) {
            const int row = (reg & 3) + 8 * (reg >> 2) + 4 * hi2;
            const size_t grow = arow0 + wr * 128 + m * 32 + row;
            const float xs = xscale[grow];
            float* crow = C + grow * OUT_F;
#pragma unroll
            for (int n = 0; n < 2; ++n)
                __builtin_nontemporal_store(
                    (float)acc[m][n][reg] * xs * wsc[n] + bs[n], crow + gcol[n]);
        }
    }
#undef STAGE_A
#undef LOADB
#undef COMPUTE
#undef TILE
}

extern "C" void kernel_launch(void* const* d_in, const int* in_sizes, int n_in,
                              void* d_out, int out_size, void* d_ws, size_t ws_size,
                              hipStream_t stream)
{
    const float* x      = (const float*)d_in[0];
    const float* ss     = (const float*)d_in[1];
    const float* wscale = (const float*)d_in[2];
    const float* bias   = (const float*)d_in[3];
    const int*   w32    = (const int*)d_in[4];
    float* out = (float*)d_out;

    const int T = in_sizes[0] / IN_F;   // 16384

    int8_t* xq     = (int8_t*)d_ws;
    float*  xscale = (float*)((char*)d_ws + (size_t)T * IN_F);
    int8_t* w8f    = (int8_t*)((char*)d_ws + (size_t)T * IN_F + (size_t)T * 4);

    quant_kernel<<<dim3((T + 3) / 4), dim3(256), 0, stream>>>(x, ss, xq, xscale, T);
    pack_wfrag_kernel<<<dim3(1024), dim3(256), 0, stream>>>(w32, w8f);
    gemm_kernel<<<dim3((T / BM) * (OUT_F / BN)), dim3(512), 0, stream>>>(
        xq, w8f, xscale, wscale, bias, out, T);
}